// Round 11
// baseline (3101.557 us; speedup 1.0000x reference)
//
#include <hip/hip_runtime.h>
#include <cstdint>
#include <cstddef>

// Problem dims (fixed by reference)
#define B_    64
#define T_    4096
#define H_    128
#define C1_   64
#define NCLS_ 40

#define LOG2E_    1.4426950408889634f
#define TWOLOG2E_ 2.8853900817779268f

typedef _Float16 half2_t __attribute__((ext_vector_type(2)));
typedef _Float16 half8_t __attribute__((ext_vector_type(8)));
typedef float    f32x4  __attribute__((ext_vector_type(4)));

__device__ __forceinline__ float fdot2(half2_t a, half2_t b, float c){
#if defined(__has_builtin) && __has_builtin(__builtin_amdgcn_fdot2)
  return __builtin_amdgcn_fdot2(a, b, c, false);
#else
  return fmaf((float)a.x, (float)b.x, fmaf((float)a.y, (float)b.y, c));
#endif
}
__device__ __forceinline__ half2_t bc2(unsigned int u){ return __builtin_bit_cast(half2_t, u); }
__device__ __forceinline__ half2_t pack2(float a, float b){
  half2_t r; r.x = (_Float16)a; r.y = (_Float16)b; return r;   // RTNE
}
template<int CTRL>
__device__ __forceinline__ float qperm(float x){
  return __int_as_float(__builtin_amdgcn_update_dpp(0, __float_as_int(x), CTRL, 0xF, 0xF, true));
}

// ---------------- kernel 1: 3x3 second-moment stats of x over B*T ----------------
__global__ __launch_bounds__(256) void stats_kernel(const float* __restrict__ x,
                                                    float* __restrict__ stats){
  int t = blockIdx.x * 256 + threadIdx.x;
  const float4* xv = (const float4*)x + (size_t)t * 3;
  float4 a = xv[0], b = xv[1], c = xv[2];
  float x0[4] = {a.x, a.w, b.z, c.y};
  float x1[4] = {a.y, b.x, b.w, c.z};
  float x2[4] = {a.z, b.y, c.x, c.w};
  float s[9] = {0,0,0,0,0,0,0,0,0};
  #pragma unroll
  for (int r=0;r<4;++r){
    s[0]+=x0[r]; s[1]+=x1[r]; s[2]+=x2[r];
    s[3]+=x0[r]*x0[r]; s[4]+=x0[r]*x1[r]; s[5]+=x0[r]*x2[r];
    s[6]+=x1[r]*x1[r]; s[7]+=x1[r]*x2[r]; s[8]+=x2[r]*x2[r];
  }
  __shared__ float red[9][256];
  #pragma unroll
  for (int j=0;j<9;++j) red[j][threadIdx.x] = s[j];
  __syncthreads();
  if (threadIdx.x < 9){
    float sum = 0.f;
    for (int i=0;i<256;++i) sum += red[threadIdx.x][i];
    atomicAdd(&stats[threadIdx.x], sum);
  }
}

// Fold conv + BN(train stats) + gamma/beta into per-channel affine. conv_b cancels.
__device__ __forceinline__ void chan_affine(int c, const float* __restrict__ conv_w,
    const float* __restrict__ bn_g, const float* __restrict__ bn_b,
    const float* __restrict__ stats,
    float& A0, float& A1, float& A2, float& Bc){
  const float Ninv = 1.0f / (float)(B_*T_);
  float m0=stats[0]*Ninv, m1=stats[1]*Ninv, m2=stats[2]*Ninv;
  float c00=stats[3]*Ninv-m0*m0, c01=stats[4]*Ninv-m0*m1, c02=stats[5]*Ninv-m0*m2;
  float c11=stats[6]*Ninv-m1*m1, c12=stats[7]*Ninv-m1*m2, c22=stats[8]*Ninv-m2*m2;
  float w0=conv_w[c*3+0], w1=conv_w[c*3+1], w2=conv_w[c*3+2];
  float var = w0*(w0*c00 + 2.f*(w1*c01 + w2*c02)) + w1*(w1*c11 + 2.f*w2*c12) + w2*w2*c22;
  float sc = bn_g[c] * rsqrtf(var + 1e-5f);
  A0 = w0*sc; A1 = w1*sc; A2 = w2*sc;
  Bc = bn_b[c] - (w0*m0 + w1*m1 + w2*m2)*sc;
}

// ---------------- kernel 2 (Tier A): y = relu(affine(x)) as f16 [B][T+4][64] ----------------
// rows T..T+3 are junk pads so the LSTM y prefetch needs no clamp
__global__ __launch_bounds__(256) void y_kernel(const float* __restrict__ x,
    const float* __restrict__ conv_w, const float* __restrict__ bn_g,
    const float* __restrict__ bn_b, const float* __restrict__ stats,
    _Float16* __restrict__ yg){
  __shared__ float4 coef[C1_];
  int tid = threadIdx.x;
  if (tid < C1_){
    float A0,A1,A2,Bc; chan_affine(tid, conv_w, bn_g, bn_b, stats, A0,A1,A2,Bc);
    coef[tid] = make_float4(A0,A1,A2,Bc);
  }
  __syncthreads();
  size_t idx = (size_t)blockIdx.x * 256 + tid;      // b*T + t
  int b = (int)(idx >> 12), t = (int)(idx & (T_-1));
  const float* xp = x + idx*3;
  float x0 = xp[0], x1 = xp[1], x2 = xp[2];
  unsigned int ob[32];
  #pragma unroll
  for (int c=0; c<C1_; c+=2){
    float4 c0 = coef[c], c1 = coef[c+1];
    float v0 = fmaxf(fmaf(c0.x,x0, fmaf(c0.y,x1, fmaf(c0.z,x2, c0.w))), 0.f);
    float v1 = fmaxf(fmaf(c1.x,x0, fmaf(c1.y,x1, fmaf(c1.z,x2, c1.w))), 0.f);
    ob[c>>1] = __builtin_bit_cast(unsigned int, pack2(v0, v1));
  }
  uint4* dst = (uint4*)(yg + ((size_t)b*(T_+4) + t)*C1_);
  #pragma unroll
  for (int i=0;i<8;++i) dst[i] = ((uint4*)ob)[i];
}

// ---------------- kernel 3 (Tier A): MFMA batch-16 LSTM ----------------
// 4 blocks x 512 threads; block handles batches [16*bid, 16*bid+16).
// Per step: gates[512x16] = Whh[512x128]@H[128x16] + Wih[512x64]@Y[64x16] via
// mfma_f32_16x16x32_f16. Wave w owns M-tiles {128g+16w rows, g=0..3} -> all 4 gates
// for k in [16w,16w+16). A-frags (weights, exp2-prescaled) resident in VGPRs.
// D layout (verified m89): col=lane&15=batch n, row=4*(lane>>4)+reg=k-local ->
// all gates lane-local: c in regs, activations without any cross-lane ops.
// B-frags read from LDS H[n][k] (+8 f16 pad -> even bank groups); h written back
// as one ds_write_b64/lane. Y staged global->reg->LDS ring-4, 2-step slack.
__global__ __launch_bounds__(512,2) void lstm_mfma_kernel(
    const _Float16* __restrict__ yg,
    const float* __restrict__ w_ih, const float* __restrict__ b_ih,
    const float* __restrict__ b_hh, const float* __restrict__ w_hh,
    const float* __restrict__ h0, const float* __restrict__ c0,
    const float* __restrict__ out_w, const float* __restrict__ out_b,
    float* __restrict__ out){
  int b0 = blockIdx.x * 16;
  int t = threadIdx.x;
  int wv = t >> 6, lane = t & 63;
  int q = lane >> 4, n = lane & 15;
  __shared__ __align__(16) _Float16 Hl[2][16][H_+8];   // [parity][batch][k], pad 8
  __shared__ __align__(16) _Float16 Yl[4][16][C1_+8];  // ring-4 [slot][batch][yk]

  // A-frags: A[m=lane&15][k=8*(lane>>4)+j] (m120). Row m of tile (8g+w) = 128g+16w+(lane&15).
  half8_t Ah[4][4];    // [gate][K-chunk of 32]
  half8_t Ay[4][2];
  f32x4 biasv[4];
  #pragma unroll
  for (int g=0; g<4; ++g){
    float sg = (g==2) ? TWOLOG2E_ : -LOG2E_;
    int row = g*H_ + 16*wv + n;
    #pragma unroll
    for (int c=0; c<4; ++c){
      const float* src = w_hh + (size_t)row*H_ + 32*c + 8*q;
      half8_t f;
      #pragma unroll
      for (int j=0;j<8;++j) f[j] = (_Float16)(sg*src[j]);
      Ah[g][c] = f;
    }
    #pragma unroll
    for (int c=0; c<2; ++c){
      const float* src = w_ih + (size_t)row*C1_ + 32*c + 8*q;
      half8_t f;
      #pragma unroll
      for (int j=0;j<8;++j) f[j] = (_Float16)(sg*src[j]);
      Ay[g][c] = f;
    }
    #pragma unroll
    for (int r=0;r<4;++r){
      int kk = 16*wv + 4*q + r;                      // D-row of this lane
      biasv[g][r] = sg * (b_ih[g*H_+kk] + b_hh[g*H_+kk]);
    }
  }
  // c state: lane owns k = 16w+4q+r, batch n (scaled by 2log2e)
  float cs[4];
  #pragma unroll
  for (int r=0;r<4;++r)
    cs[r] = TWOLOG2E_ * c0[(size_t)(b0+n)*H_ + 16*wv + 4*q + r];

  // init H(-1) and Y slots 0,1
  { int nn = t >> 5, kk = (t & 31) * 4;              // 512 threads x 4 f16
    const float* hsrc = h0 + (size_t)(b0+nn)*H_ + kk;
    _Float16* hd = &Hl[0][nn][kk];
    hd[0]=(_Float16)hsrc[0]; hd[1]=(_Float16)hsrc[1];
    hd[2]=(_Float16)hsrc[2]; hd[3]=(_Float16)hsrc[3];
    int col = (t & 31) * 2;
    const _Float16* ysrc = yg + (size_t)(b0+nn)*(T_+4)*C1_ + col;
    *(unsigned int*)&Yl[0][nn][col] = *(const unsigned int*)(ysrc);
    *(unsigned int*)&Yl[1][nn][col] = *(const unsigned int*)(ysrc + C1_);
  }
  // y pipeline: yprev = Y(2)
  int yn_ = t >> 5, ycol = (t & 31) * 2;
  const _Float16* ygrow = yg + (size_t)(b0+yn_)*(T_+4)*C1_ + ycol;
  unsigned int yprev = *(const unsigned int*)(ygrow + 2*C1_);
  __syncthreads();

  #pragma unroll 4
  for (int step=0; step<T_; ++step){
    int p  = step & 1;
    int yr = step & 3;
    // stage yprev (=Y(step+2)) into ring slot (step+2)&3; issue load of Y(step+3)
    *(unsigned int*)&Yl[(step+2)&3][yn_][ycol] = yprev;        // waits vmcnt (1 step in flight)
    yprev = *(const unsigned int*)(ygrow + (size_t)(step+3)*C1_);  // rows T..T+3 are pads
    // B-frags: B[k=8q+j][n=lane&15] from [batch][k] LDS rows
    f32x4 acc0 = biasv[0], acc1 = biasv[1], acc2 = biasv[2], acc3 = biasv[3];
    half8_t By0 = *(const half8_t*)&Yl[yr][n][8*q];
    half8_t By1 = *(const half8_t*)&Yl[yr][n][32 + 8*q];
    acc0 = __builtin_amdgcn_mfma_f32_16x16x32_f16(Ay[0][0], By0, acc0, 0,0,0);
    acc1 = __builtin_amdgcn_mfma_f32_16x16x32_f16(Ay[1][0], By0, acc1, 0,0,0);
    acc2 = __builtin_amdgcn_mfma_f32_16x16x32_f16(Ay[2][0], By0, acc2, 0,0,0);
    acc3 = __builtin_amdgcn_mfma_f32_16x16x32_f16(Ay[3][0], By0, acc3, 0,0,0);
    acc0 = __builtin_amdgcn_mfma_f32_16x16x32_f16(Ay[0][1], By1, acc0, 0,0,0);
    acc1 = __builtin_amdgcn_mfma_f32_16x16x32_f16(Ay[1][1], By1, acc1, 0,0,0);
    acc2 = __builtin_amdgcn_mfma_f32_16x16x32_f16(Ay[2][1], By1, acc2, 0,0,0);
    acc3 = __builtin_amdgcn_mfma_f32_16x16x32_f16(Ay[3][1], By1, acc3, 0,0,0);
    #pragma unroll
    for (int c=0; c<4; ++c){
      half8_t Bh = *(const half8_t*)&Hl[p][n][32*c + 8*q];
      acc0 = __builtin_amdgcn_mfma_f32_16x16x32_f16(Ah[0][c], Bh, acc0, 0,0,0);
      acc1 = __builtin_amdgcn_mfma_f32_16x16x32_f16(Ah[1][c], Bh, acc1, 0,0,0);
      acc2 = __builtin_amdgcn_mfma_f32_16x16x32_f16(Ah[2][c], Bh, acc2, 0,0,0);
      acc3 = __builtin_amdgcn_mfma_f32_16x16x32_f16(Ah[3][c], Bh, acc3, 0,0,0);
    }
    // lane-local cell update for 4 k's (prescaled exp2 forms)
    _Float16 hh[4];
    #pragma unroll
    for (int r=0;r<4;++r){
      float Is = TWOLOG2E_ * __builtin_amdgcn_rcpf(1.f + __builtin_amdgcn_exp2f(acc0[r]));
      float F  = __builtin_amdgcn_rcpf(1.f + __builtin_amdgcn_exp2f(acc1[r]));
      float G  = fmaf(-2.f, __builtin_amdgcn_rcpf(1.f + __builtin_amdgcn_exp2f(acc2[r])), 1.f);
      float O  = __builtin_amdgcn_rcpf(1.f + __builtin_amdgcn_exp2f(acc3[r]));
      cs[r] = fmaf(F, cs[r], Is*G);
      float th = fmaf(-2.f, __builtin_amdgcn_rcpf(1.f + __builtin_amdgcn_exp2f(cs[r])), 1.f);
      hh[r] = (_Float16)(th * O);
    }
    *(double*)&Hl[1-p][n][16*wv + 4*q] = *(double*)hh;   // b64: h for 4 k's, batch n
    asm volatile("s_waitcnt lgkmcnt(0)" ::: "memory");
    __builtin_amdgcn_s_barrier();
    asm volatile("" ::: "memory");
  }
  __syncthreads();
  // classifier epilogue: h(T-1) in Hl[0]
  for (int i = t; i < 16*NCLS_; i += 512){
    int nn = i / NCLS_, cls = i - nn*NCLS_;
    float s = out_b[cls];
    #pragma unroll 8
    for (int kk=0; kk<H_; ++kk)
      s = fmaf(out_w[cls*H_ + kk], (float)Hl[0][nn][kk], s);
    out[(size_t)(b0+nn)*NCLS_ + cls] = s;
  }
}

// ---------------- Tier B fallback: R10 barrier kernel, in-kernel y ----------------
__global__ __launch_bounds__(512,2) void lstm_fb_kernel(
    const float* __restrict__ x,
    const float* __restrict__ conv_w, const float* __restrict__ bn_g,
    const float* __restrict__ bn_b, const float* __restrict__ stats,
    const float* __restrict__ w_ih, const float* __restrict__ b_ih,
    const float* __restrict__ b_hh, const float* __restrict__ w_hh,
    const float* __restrict__ h0, const float* __restrict__ c0,
    const float* __restrict__ out_w, const float* __restrict__ out_b,
    float* __restrict__ out){
  int b = blockIdx.x, t = threadIdx.x;
  int k = t >> 2, w = t & 3;
  __shared__ __align__(16) _Float16 hbuf[2][H_];
  __shared__ __align__(16) _Float16 ybuf[4][C1_];
  half2_t wh[4][16];
  half2_t wy[4][8];
  #pragma unroll
  for (int g=0; g<4; ++g){
    float sg = (g==2) ? TWOLOG2E_ : -LOG2E_;
    const float4* p = (const float4*)(w_hh + (size_t)(g*H_ + k)*H_ + w*32);
    #pragma unroll
    for (int i=0;i<8;++i){
      float4 v = p[i];
      wh[g][2*i]   = pack2(sg*v.x, sg*v.y);
      wh[g][2*i+1] = pack2(sg*v.z, sg*v.w);
    }
    const float4* py = (const float4*)(w_ih + (size_t)(g*H_ + k)*C1_ + w*16);
    #pragma unroll
    for (int i=0;i<4;++i){
      float4 v = py[i];
      wy[g][2*i]   = pack2(sg*v.x, sg*v.y);
      wy[g][2*i+1] = pack2(sg*v.z, sg*v.w);
    }
  }
  float biasSel;
  { float sg = (w==2) ? TWOLOG2E_ : -LOG2E_;
    biasSel = sg * (b_ih[w*H_+k] + b_hh[w*H_+k]); }
  float Aa = (w==2) ?  1.f : 0.f;
  float Bb = (w==0) ? TWOLOG2E_ : ((w==2) ? -2.f : 1.f);
  bool o1 = (w & 1) != 0;
  bool o2 = (w & 2) != 0;
  float cs = TWOLOG2E_ * c0[(size_t)b*H_ + k];
  if (w == 0) hbuf[0][k] = (_Float16)h0[(size_t)b*H_ + k];
  int yc = t >> 3; bool prod = ((t & 7) == 0);
  float ya0=0, ya1=0, ya2=0, ya3=0;
  float xs0=0, xs1=0, xs2=0, xn0=0, xn1=0, xn2=0;
  const float* xb = x + (size_t)b*T_*3;
  chan_affine(yc, conv_w, bn_g, bn_b, stats, ya0, ya1, ya2, ya3);
  if (prod){
    float v0 = fmaf(ya0, xb[0], fmaf(ya1, xb[1], fmaf(ya2, xb[2], ya3)));
    float v1 = fmaf(ya0, xb[3], fmaf(ya1, xb[4], fmaf(ya2, xb[5], ya3)));
    ybuf[0][yc] = (_Float16)fmaxf(v0, 0.f);
    ybuf[1][yc] = (_Float16)fmaxf(v1, 0.f);
  }
  xs0 = xb[6];  xs1 = xb[7];  xs2 = xb[8];
  xn0 = xb[9];  xn1 = xb[10]; xn2 = xb[11];
  __syncthreads();
  #pragma unroll 2
  for (int step=0; step<T_; ++step){
    int p = step & 1;
    float acc[4] = {0.f,0.f,0.f,0.f};
    const _Float16* yb2 = &ybuf[step & 3][w*16];
    uint4 yv0 = *(const uint4*)(yb2);
    uint4 yv1 = *(const uint4*)(yb2 + 8);
    half2_t y0_ = bc2(yv0.x), y1_ = bc2(yv0.y), y2_ = bc2(yv0.z), y3_ = bc2(yv0.w);
    half2_t y4_ = bc2(yv1.x), y5_ = bc2(yv1.y), y6_ = bc2(yv1.z), y7_ = bc2(yv1.w);
    #pragma unroll
    for (int g=0; g<4; ++g){
      acc[g] = fdot2(wy[g][0], y0_, acc[g]);
      acc[g] = fdot2(wy[g][1], y1_, acc[g]);
      acc[g] = fdot2(wy[g][2], y2_, acc[g]);
      acc[g] = fdot2(wy[g][3], y3_, acc[g]);
      acc[g] = fdot2(wy[g][4], y4_, acc[g]);
      acc[g] = fdot2(wy[g][5], y5_, acc[g]);
      acc[g] = fdot2(wy[g][6], y6_, acc[g]);
      acc[g] = fdot2(wy[g][7], y7_, acc[g]);
    }
    float yn = fmaf(ya0, xs0, fmaf(ya1, xs1, fmaf(ya2, xs2, ya3)));
    if (prod) ybuf[(step+2) & 3][yc] = (_Float16)fmaxf(yn, 0.f);
    xs0=xn0; xs1=xn1; xs2=xn2;
    { int t4 = (step+4 < T_) ? step+4 : T_-1;
      const float* xp = xb + 3*t4; xn0=xp[0]; xn1=xp[1]; xn2=xp[2]; }
    asm volatile("s_waitcnt lgkmcnt(0)" ::: "memory");
    __builtin_amdgcn_s_barrier();
    asm volatile("" ::: "memory");
    const _Float16* hb = &hbuf[p][w*32];
    #pragma unroll
    for (int i=0;i<4;++i){
      uint4 hv = *(const uint4*)(hb + 8*i);
      half2_t h0_ = bc2(hv.x), h1_ = bc2(hv.y), h2_ = bc2(hv.z), h3_ = bc2(hv.w);
      #pragma unroll
      for (int g=0; g<4; ++g){
        acc[g] = fdot2(wh[g][4*i+0], h0_, acc[g]);
        acc[g] = fdot2(wh[g][4*i+1], h1_, acc[g]);
        acc[g] = fdot2(wh[g][4*i+2], h2_, acc[g]);
        acc[g] = fdot2(wh[g][4*i+3], h3_, acc[g]);
      }
    }
    float b01, b23;
    { float s0 = o1 ? acc[0] : acc[1];  float k0 = o1 ? acc[1] : acc[0];
      float s1 = o1 ? acc[2] : acc[3];  float k1 = o1 ? acc[3] : acc[2];
      b01 = k0 + qperm<0xB1>(s0);
      b23 = k1 + qperm<0xB1>(s1); }
    float accv;
    { float s = o2 ? b01 : b23;  float kk = o2 ? b23 : b01;
      accv = kk + qperm<0x4E>(s); }
    float v = accv + biasSel;
    float e = __builtin_amdgcn_exp2f(v);
    float act = fmaf(Bb, __builtin_amdgcn_rcpf(1.f + e), Aa);
    float dA = qperm<0x1B>(act);
    float bp = qperm<0x4E>(act);
    float pp = act * (o1 ? cs : bp);
    float cps = pp + qperm<0xB1>(pp);
    cps = qperm<0x00>(cps);
    cs = cps;
    float th = fmaf(-2.f, __builtin_amdgcn_rcpf(1.f + __builtin_amdgcn_exp2f(cps)), 1.f);
    float h = th * dA;
    if (w == 0) hbuf[1-p][k] = (_Float16)h;
  }
  __syncthreads();
  if (t < NCLS_){
    float s = out_b[t];
    #pragma unroll 8
    for (int kk=0; kk<H_; ++kk)
      s = fmaf(out_w[t*H_ + kk], (float)hbuf[0][kk], s);
    out[(size_t)b*NCLS_ + t] = s;
  }
}

extern "C" void kernel_launch(void* const* d_in, const int* in_sizes, int n_in,
                              void* d_out, int out_size, void* d_ws, size_t ws_size,
                              hipStream_t stream){
  const float* x      = (const float*)d_in[0];
  const float* conv_w = (const float*)d_in[1];
  // d_in[2] = conv_b: cancels exactly inside BN(train stats) — unused
  const float* bn_g   = (const float*)d_in[3];
  const float* bn_b   = (const float*)d_in[4];
  const float* w_ih   = (const float*)d_in[5];
  const float* b_ih   = (const float*)d_in[6];
  const float* w_hh   = (const float*)d_in[7];
  const float* b_hh   = (const float*)d_in[8];
  const float* out_w  = (const float*)d_in[9];
  const float* out_b  = (const float*)d_in[10];
  const float* h0     = (const float*)d_in[11];
  const float* c0     = (const float*)d_in[12];
  float* out      = (float*)d_out;
  float* stats    = (float*)d_ws;
  _Float16* yg    = (_Float16*)((char*)d_ws + 4096);
  const size_t needA = 4096 + (size_t)B_*(T_+4)*C1_*sizeof(_Float16);   // ~33.6 MB

  hipMemsetAsync(d_ws, 0, 64, stream);
  stats_kernel<<<256, 256, 0, stream>>>(x, stats);
  if (ws_size >= needA){
    y_kernel<<<(B_*T_)/256, 256, 0, stream>>>(x, conv_w, bn_g, bn_b, stats, yg);
    lstm_mfma_kernel<<<B_/16, 512, 0, stream>>>(yg, w_ih, b_ih, b_hh, w_hh,
                                                h0, c0, out_w, out_b, out);
  } else {
    lstm_fb_kernel<<<B_, 512, 0, stream>>>(x, conv_w, bn_g, bn_b, stats,
                                           w_ih, b_ih, b_hh, w_hh, h0, c0,
                                           out_w, out_b, out);
  }
}

// Round 12
// 2370.852 us; speedup vs baseline: 1.3082x; 1.3082x over previous
//
#include <hip/hip_runtime.h>
#include <cstdint>
#include <cstddef>

// Problem dims (fixed by reference)
#define B_    64
#define T_    4096
#define H_    128
#define C1_   64
#define NCLS_ 40

#define LOG2E_    1.4426950408889634f
#define TWOLOG2E_ 2.8853900817779268f

typedef _Float16 half2_t __attribute__((ext_vector_type(2)));

__device__ __forceinline__ float fdot2(half2_t a, half2_t b, float c){
#if defined(__has_builtin) && __has_builtin(__builtin_amdgcn_fdot2)
  return __builtin_amdgcn_fdot2(a, b, c, false);   // v_dot2_f32_f16, full-rate
#else
  return fmaf((float)a.x, (float)b.x, fmaf((float)a.y, (float)b.y, c));
#endif
}
__device__ __forceinline__ half2_t bc2(unsigned int u){ return __builtin_bit_cast(half2_t, u); }
__device__ __forceinline__ half2_t pack2(float a, float b){
  half2_t r; r.x = (_Float16)a; r.y = (_Float16)b; return r;   // RTNE
}
template<int CTRL>
__device__ __forceinline__ float qperm(float x){
  return __int_as_float(__builtin_amdgcn_update_dpp(0, __float_as_int(x), CTRL, 0xF, 0xF, true));
}

// ---------------- kernel 1: 3x3 second-moment stats of x over B*T ----------------
__global__ __launch_bounds__(256) void stats_kernel(const float* __restrict__ x,
                                                    float* __restrict__ stats){
  int t = blockIdx.x * 256 + threadIdx.x;
  const float4* xv = (const float4*)x + (size_t)t * 3;
  float4 a = xv[0], b = xv[1], c = xv[2];
  float x0[4] = {a.x, a.w, b.z, c.y};
  float x1[4] = {a.y, b.x, b.w, c.z};
  float x2[4] = {a.z, b.y, c.x, c.w};
  float s[9] = {0,0,0,0,0,0,0,0,0};
  #pragma unroll
  for (int r=0;r<4;++r){
    s[0]+=x0[r]; s[1]+=x1[r]; s[2]+=x2[r];
    s[3]+=x0[r]*x0[r]; s[4]+=x0[r]*x1[r]; s[5]+=x0[r]*x2[r];
    s[6]+=x1[r]*x1[r]; s[7]+=x1[r]*x2[r]; s[8]+=x2[r]*x2[r];
  }
  __shared__ float red[9][256];
  #pragma unroll
  for (int j=0;j<9;++j) red[j][threadIdx.x] = s[j];
  __syncthreads();
  if (threadIdx.x < 9){
    float sum = 0.f;
    for (int i=0;i<256;++i) sum += red[threadIdx.x][i];
    atomicAdd(&stats[threadIdx.x], sum);
  }
}

// Fold conv + BN(train stats) + gamma/beta into per-channel affine. conv_b cancels.
__device__ __forceinline__ void chan_affine(int c, const float* __restrict__ conv_w,
    const float* __restrict__ bn_g, const float* __restrict__ bn_b,
    const float* __restrict__ stats,
    float& A0, float& A1, float& A2, float& Bc){
  const float Ninv = 1.0f / (float)(B_*T_);
  float m0=stats[0]*Ninv, m1=stats[1]*Ninv, m2=stats[2]*Ninv;
  float c00=stats[3]*Ninv-m0*m0, c01=stats[4]*Ninv-m0*m1, c02=stats[5]*Ninv-m0*m2;
  float c11=stats[6]*Ninv-m1*m1, c12=stats[7]*Ninv-m1*m2, c22=stats[8]*Ninv-m2*m2;
  float w0=conv_w[c*3+0], w1=conv_w[c*3+1], w2=conv_w[c*3+2];
  float var = w0*(w0*c00 + 2.f*(w1*c01 + w2*c02)) + w1*(w1*c11 + 2.f*w2*c12) + w2*w2*c22;
  float sc = bn_g[c] * rsqrtf(var + 1e-5f);
  A0 = w0*sc; A1 = w1*sc; A2 = w2*sc;
  Bc = bn_b[c] - (w0*m0 + w1*m1 + w2*m2)*sc;
}

// ---------------- kernel 2 (Tier A): y = relu(affine(x)) as f16 [B][T+2][64] ----------------
// rows T, T+1 are junk pads so the LSTM prefetch needs no clamp
__global__ __launch_bounds__(256) void y_kernel(const float* __restrict__ x,
    const float* __restrict__ conv_w, const float* __restrict__ bn_g,
    const float* __restrict__ bn_b, const float* __restrict__ stats,
    _Float16* __restrict__ yg){
  __shared__ float4 coef[C1_];
  int tid = threadIdx.x;
  if (tid < C1_){
    float A0,A1,A2,Bc; chan_affine(tid, conv_w, bn_g, bn_b, stats, A0,A1,A2,Bc);
    coef[tid] = make_float4(A0,A1,A2,Bc);
  }
  __syncthreads();
  size_t idx = (size_t)blockIdx.x * 256 + tid;      // b*T + t
  int b = (int)(idx >> 12), t = (int)(idx & (T_-1));
  const float* xp = x + idx*3;
  float x0 = xp[0], x1 = xp[1], x2 = xp[2];
  unsigned int ob[32];
  #pragma unroll
  for (int c=0; c<C1_; c+=2){
    float4 c0 = coef[c], c1 = coef[c+1];
    float v0 = fmaxf(fmaf(c0.x,x0, fmaf(c0.y,x1, fmaf(c0.z,x2, c0.w))), 0.f);
    float v1 = fmaxf(fmaf(c1.x,x0, fmaf(c1.y,x1, fmaf(c1.z,x2, c1.w))), 0.f);
    ob[c>>1] = __builtin_bit_cast(unsigned int, pack2(v0, v1));
  }
  uint4* dst = (uint4*)(yg + ((size_t)b*(T_+2) + t)*C1_);
  #pragma unroll
  for (int i=0;i<8;++i) dst[i] = ((uint4*)ob)[i];
}

// ---------------- kernel 3: persistent per-batch LSTM (R10 structure, tail-trimmed) ----------------
// 64 blocks x 512 threads (8 waves, 2/SIMD — measured optimum: 4w=1578, 8w=1362,
// 16w=1688 cyc/step; MFMA batch-16 = 1763, trans-floor-bound). thread t: k=t>>2,
// w=t&3 (32-wide h window / 16-wide y window). Pre-barrier: y-dots + depth-2 y
// prefetch (ring-4 regs, pointer-bumped). Raw s_barrier + lgkmcnt(0) (vmcnt loads
// stay in flight). Gate exp2-scales folded into W/bias; c carried scaled by 2log2e.
// Tail: no c-broadcast (lanes 2,3 cs unused), dA hoisted off the cps chain.
template<bool YG>
__global__ __launch_bounds__(512,2) void lstm_kernel(
    const _Float16* __restrict__ yg, const float* __restrict__ x,
    const float* __restrict__ conv_w, const float* __restrict__ bn_g,
    const float* __restrict__ bn_b, const float* __restrict__ stats,
    const float* __restrict__ w_ih, const float* __restrict__ b_ih,
    const float* __restrict__ b_hh, const float* __restrict__ w_hh,
    const float* __restrict__ h0, const float* __restrict__ c0,
    const float* __restrict__ out_w, const float* __restrict__ out_b,
    float* __restrict__ out){
  int b = blockIdx.x, t = threadIdx.x;
  int k = t >> 2, w = t & 3;
  __shared__ __align__(16) _Float16 hbuf[2][H_];
  __shared__ __align__(16) _Float16 ybuf[4][C1_];   // Tier B mod-4 ring

  // weights prescaled by gate exp2-scale: sg = -log2e (I,F,O), +2log2e (G)
  half2_t wh[4][16];
  half2_t wy[4][8];
  #pragma unroll
  for (int g=0; g<4; ++g){
    float sg = (g==2) ? TWOLOG2E_ : -LOG2E_;
    const float4* p = (const float4*)(w_hh + (size_t)(g*H_ + k)*H_ + w*32);
    #pragma unroll
    for (int i=0;i<8;++i){
      float4 v = p[i];
      wh[g][2*i]   = pack2(sg*v.x, sg*v.y);
      wh[g][2*i+1] = pack2(sg*v.z, sg*v.w);
    }
    const float4* py = (const float4*)(w_ih + (size_t)(g*H_ + k)*C1_ + w*16);
    #pragma unroll
    for (int i=0;i<4;++i){
      float4 v = py[i];
      wy[g][2*i]   = pack2(sg*v.x, sg*v.y);
      wy[g][2*i+1] = pack2(sg*v.z, sg*v.w);
    }
  }
  float biasSel;
  { float sg = (w==2) ? TWOLOG2E_ : -LOG2E_;
    biasSel = sg * (b_ih[w*H_+k] + b_hh[w*H_+k]); }
  float Aa = (w==2) ?  1.f : 0.f;
  float Bb = (w==0) ? TWOLOG2E_ : ((w==2) ? -2.f : 1.f);
  bool o1 = (w & 1) != 0;
  bool o2 = (w & 2) != 0;

  float cs = TWOLOG2E_ * c0[(size_t)b*H_ + k];      // scaled cell state (lanes 0,1 authoritative)
  if (w == 0) hbuf[0][k] = (_Float16)h0[(size_t)b*H_ + k];

  // ---- Tier B (in-kernel y) setup ----
  int yc = t >> 3; bool prod = ((t & 7) == 0);
  float ya0=0, ya1=0, ya2=0, ya3=0;
  float xs0=0, xs1=0, xs2=0, xn0=0, xn1=0, xn2=0;
  const float* xb = x + (size_t)b*T_*3;
  if constexpr (!YG){
    chan_affine(yc, conv_w, bn_g, bn_b, stats, ya0, ya1, ya2, ya3);
    if (prod){
      float v0 = fmaf(ya0, xb[0], fmaf(ya1, xb[1], fmaf(ya2, xb[2], ya3)));
      float v1 = fmaf(ya0, xb[3], fmaf(ya1, xb[4], fmaf(ya2, xb[5], ya3)));
      ybuf[0][yc] = (_Float16)fmaxf(v0, 0.f);
      ybuf[1][yc] = (_Float16)fmaxf(v1, 0.f);
    }
    xs0 = xb[6];  xs1 = xb[7];  xs2 = xb[8];        // x[2]
    xn0 = xb[9];  xn1 = xb[10]; xn2 = xb[11];       // x[3]
  }
  // ---- Tier A y preload: depth-2 prefetch, ring-4 register buffers, bumped pointer ----
  const _Float16* ypref = nullptr;
  uint4 ypf[4][2];
  if constexpr (YG){
    const _Float16* ygb = yg + (size_t)b*(T_+2)*C1_ + w*16;
    ypf[0][0] = *(const uint4*)(ygb);           ypf[0][1] = *(const uint4*)(ygb + 8);
    ypf[1][0] = *(const uint4*)(ygb + C1_);     ypf[1][1] = *(const uint4*)(ygb + C1_ + 8);
    ypref = ygb + 2*C1_;                        // -> y(step+2) at step=0
  }
  __syncthreads();

  #pragma unroll 4
  for (int step=0; step<T_; ++step){
    int p  = step & 1;                              // const-folded per unrolled copy
    int r4 = step & 3;
    float acc[4] = {0.f,0.f,0.f,0.f};
    // ===== pre-barrier: prefetch y(step+2) (pointer bump), then y-dots =====
    if constexpr (YG){
      ypf[(r4+2)&3][0] = *(const uint4*)(ypref);           // vmcnt; used 2 iters later
      ypf[(r4+2)&3][1] = *(const uint4*)(ypref + 8);
      ypref += C1_;                                        // rows T,T+1 are pads — no clamp
      uint4 yv0 = ypf[r4][0], yv1 = ypf[r4][1];
      half2_t y0_ = bc2(yv0.x), y1_ = bc2(yv0.y), y2_ = bc2(yv0.z), y3_ = bc2(yv0.w);
      half2_t y4_ = bc2(yv1.x), y5_ = bc2(yv1.y), y6_ = bc2(yv1.z), y7_ = bc2(yv1.w);
      #pragma unroll
      for (int g=0; g<4; ++g){
        acc[g] = fdot2(wy[g][0], y0_, acc[g]);
        acc[g] = fdot2(wy[g][1], y1_, acc[g]);
        acc[g] = fdot2(wy[g][2], y2_, acc[g]);
        acc[g] = fdot2(wy[g][3], y3_, acc[g]);
        acc[g] = fdot2(wy[g][4], y4_, acc[g]);
        acc[g] = fdot2(wy[g][5], y5_, acc[g]);
        acc[g] = fdot2(wy[g][6], y6_, acc[g]);
        acc[g] = fdot2(wy[g][7], y7_, acc[g]);
      }
    } else {
      const _Float16* yb2 = &ybuf[r4][w*16];        // written >=2 barriers ago
      uint4 yv0 = *(const uint4*)(yb2);
      uint4 yv1 = *(const uint4*)(yb2 + 8);
      half2_t y0_ = bc2(yv0.x), y1_ = bc2(yv0.y), y2_ = bc2(yv0.z), y3_ = bc2(yv0.w);
      half2_t y4_ = bc2(yv1.x), y5_ = bc2(yv1.y), y6_ = bc2(yv1.z), y7_ = bc2(yv1.w);
      #pragma unroll
      for (int g=0; g<4; ++g){
        acc[g] = fdot2(wy[g][0], y0_, acc[g]);
        acc[g] = fdot2(wy[g][1], y1_, acc[g]);
        acc[g] = fdot2(wy[g][2], y2_, acc[g]);
        acc[g] = fdot2(wy[g][3], y3_, acc[g]);
        acc[g] = fdot2(wy[g][4], y4_, acc[g]);
        acc[g] = fdot2(wy[g][5], y5_, acc[g]);
        acc[g] = fdot2(wy[g][6], y6_, acc[g]);
        acc[g] = fdot2(wy[g][7], y7_, acc[g]);
      }
      float yn = fmaf(ya0, xs0, fmaf(ya1, xs1, fmaf(ya2, xs2, ya3)));
      if (prod) ybuf[(step+2) & 3][yc] = (_Float16)fmaxf(yn, 0.f);   // y[step+2]
      xs0=xn0; xs1=xn1; xs2=xn2;
      { int t4 = (step+4 < T_) ? step+4 : T_-1;
        const float* xp = xb + 3*t4; xn0=xp[0]; xn1=xp[1]; xn2=xp[2]; }
    }
    // ===== barrier (LDS-only drain; vmcnt loads stay in flight) =====
    asm volatile("s_waitcnt lgkmcnt(0)" ::: "memory");
    __builtin_amdgcn_s_barrier();
    asm volatile("" ::: "memory");
    // ===== post-barrier: h-dots over [w*32, w*32+32) =====
    const _Float16* hb = &hbuf[p][w*32];
    #pragma unroll
    for (int i=0;i<4;++i){
      uint4 hv = *(const uint4*)(hb + 8*i);
      half2_t h0_ = bc2(hv.x), h1_ = bc2(hv.y), h2_ = bc2(hv.z), h3_ = bc2(hv.w);
      #pragma unroll
      for (int g=0; g<4; ++g){
        acc[g] = fdot2(wh[g][4*i+0], h0_, acc[g]);
        acc[g] = fdot2(wh[g][4*i+1], h1_, acc[g]);
        acc[g] = fdot2(wh[g][4*i+2], h2_, acc[g]);
        acc[g] = fdot2(wh[g][4*i+3], h3_, acc[g]);
      }
    }
    // reduce-scatter over quad: lane w ends with gate w's total
    float b01, b23;
    { float s0 = o1 ? acc[0] : acc[1];  float k0 = o1 ? acc[1] : acc[0];
      float s1 = o1 ? acc[2] : acc[3];  float k1 = o1 ? acc[3] : acc[2];
      b01 = k0 + qperm<0xB1>(s0);
      b23 = k1 + qperm<0xB1>(s1); }
    float accv;
    { float s = o2 ? b01 : b23;  float kk = o2 ? b23 : b01;
      accv = kk + qperm<0x4E>(s); }
    // activation (prescaled): act = Aa + Bb*rcp(1+exp2(v))
    float v = accv + biasSel;
    float e = __builtin_amdgcn_exp2f(v);
    float act = fmaf(Bb, __builtin_amdgcn_rcpf(1.f + e), Aa);
    // recombine: dA/bp hoisted (parallel); cs' valid in lanes 0,1 only — lanes 2,3
    // cs is garbage but never consumed (pp uses cs only in odd lanes; h from lane 0).
    float dA = qperm<0x1B>(act);                    // lane0 <- O
    float bp = qperm<0x4E>(act);                    // lane0 <- G
    float pp = act * (o1 ? cs : bp);                // lane0: I_s*G ; lane1: F*cs
    float cps = pp + qperm<0xB1>(pp);               // lanes 0,1: scaled c'
    cs = cps;                                       // no quad broadcast
    float th = fmaf(-2.f, __builtin_amdgcn_rcpf(1.f + __builtin_amdgcn_exp2f(cps)), 1.f);
    float h = th * dA;
    if (w == 0) hbuf[1-p][k] = (_Float16)h;
  }
  __syncthreads();
  // classifier epilogue on final h (T even -> buffer 0)
  if (t < NCLS_){
    float s = out_b[t];
    #pragma unroll 8
    for (int kk=0; kk<H_; ++kk)
      s = fmaf(out_w[t*H_ + kk], (float)hbuf[0][kk], s);
    out[(size_t)b*NCLS_ + t] = s;
  }
}

extern "C" void kernel_launch(void* const* d_in, const int* in_sizes, int n_in,
                              void* d_out, int out_size, void* d_ws, size_t ws_size,
                              hipStream_t stream){
  const float* x      = (const float*)d_in[0];
  const float* conv_w = (const float*)d_in[1];
  // d_in[2] = conv_b: cancels exactly inside BN(train stats) — unused
  const float* bn_g   = (const float*)d_in[3];
  const float* bn_b   = (const float*)d_in[4];
  const float* w_ih   = (const float*)d_in[5];
  const float* b_ih   = (const float*)d_in[6];
  const float* w_hh   = (const float*)d_in[7];
  const float* b_hh   = (const float*)d_in[8];
  const float* out_w  = (const float*)d_in[9];
  const float* out_b  = (const float*)d_in[10];
  const float* h0     = (const float*)d_in[11];
  const float* c0     = (const float*)d_in[12];
  float* out      = (float*)d_out;
  float* stats    = (float*)d_ws;
  _Float16* yg    = (_Float16*)((char*)d_ws + 4096);
  const size_t needA = 4096 + (size_t)B_*(T_+2)*C1_*sizeof(_Float16);   // ~33.6 MB

  hipMemsetAsync(d_ws, 0, 64, stream);
  stats_kernel<<<256, 256, 0, stream>>>(x, stats);
  if (ws_size >= needA){
    y_kernel<<<(B_*T_)/256, 256, 0, stream>>>(x, conv_w, bn_g, bn_b, stats, yg);
    lstm_kernel<true><<<B_, 512, 0, stream>>>(yg, x, conv_w, bn_g, bn_b, stats,
                                              w_ih, b_ih, b_hh, w_hh, h0, c0, out_w, out_b, out);
  } else {
    lstm_kernel<false><<<B_, 512, 0, stream>>>(yg, x, conv_w, bn_g, bn_b, stats,
                                               w_ih, b_ih, b_hh, w_hh, h0, c0, out_w, out_b, out);
  }
}